// Round 7
// baseline (114.954 us; speedup 1.0000x reference)
//
#include <hip/hip_runtime.h>

// Always (smoothed-min sliding window, W=16) over [B,T,D] fp32, two traces.
// out[b,t,d] = -log( sum_{j=0..15} exp(-5 x[b, max(t-15+j,0), d]) ) / 5
//
// R7: LCH=64 software-pipelined van Herk. Halo overhead drops from +100%
// (R6, LCH=16) to +25% of reads. Each 16-step block's loads are issued
// BEFORE the previous block's exp/scan/store phase via
// __builtin_amdgcn_sched_barrier(0) fences (the R6 trick, applied per
// block): 16 dwordx4 (16 KB/wave) stay in flight through every compute
// phase. Fully unrolled -> SSA, no register copies. ~230 VGPR state,
// launch_bounds(256,2). 1024 waves = 1/SIMD; latency hiding comes from
// per-wave MLP (64 KB in flight per CU >> ~9 KB needed for peak BW).

#define TT     8192
#define DD     64
#define BB     16
#define LCH    64            // t-steps per wave
#define CHUNKS (TT / LCH)    // 128

typedef float vfloat4 __attribute__((ext_vector_type(4)));

__device__ __forceinline__ float4 exp4n(float4 v) {
    float4 r;
    r.x = __expf(-5.0f * v.x);
    r.y = __expf(-5.0f * v.y);
    r.z = __expf(-5.0f * v.z);
    r.w = __expf(-5.0f * v.w);
    return r;
}
__device__ __forceinline__ float4 add4(float4 a, float4 b) {
    return make_float4(a.x + b.x, a.y + b.y, a.z + b.z, a.w + b.w);
}
__device__ __forceinline__ vfloat4 mlog4(float4 v) {
    vfloat4 r;
    r.x = -0.2f * __logf(v.x);
    r.y = -0.2f * __logf(v.y);
    r.z = -0.2f * __logf(v.z);
    r.w = -0.2f * __logf(v.w);
    return r;
}

__global__ __launch_bounds__(256, 2) void always_minish_v7(
    const float* __restrict__ lower,
    const float* __restrict__ upper,
    float* __restrict__ out)
{
    const int lane  = threadIdx.x & 63;
    const int wv    = (blockIdx.x << 2) | (threadIdx.x >> 6);
    const int dq    = lane & 15;           // d-quad: channels 4*dq .. 4*dq+3
    const int sq    = lane >> 4;           // seq within group of 4
    const int g     = wv >> 7;             // seq group 0..7
    const int chunk = wv & (CHUNKS - 1);   // 0..127
    const int seq   = (g << 2) | sq;       // 0..31 = trace*16 + b
    const int tr    = seq >> 4;
    const int b     = seq & 15;

    const float* __restrict__ src =
        (tr ? upper : lower) + (size_t)b * TT * DD + dq * 4;
    float* __restrict__ dst = out + (size_t)seq * TT * DD + dq * 4;

    const int t0 = chunk * LCH;

    // ---- Prologue: halo loads + block-0 loads, all in flight ----
    float4 s[16], f[16];
    #pragma unroll
    for (int j = 0; j < 16; ++j) {
        int t = t0 - 16 + j;               // clamped halo = h0 broadcast pad
        if (t < 0) t = 0;
        s[j] = *(const float4*)(src + (size_t)t * DD);
    }
    #pragma unroll
    for (int k = 0; k < 16; ++k)
        f[k] = *(const float4*)(src + (size_t)(t0 + k) * DD);
    __builtin_amdgcn_sched_barrier(0);

    // exp + suffix of halo (block-0 loads still in flight)
    #pragma unroll
    for (int j = 0; j < 16; ++j) s[j] = exp4n(s[j]);
    #pragma unroll
    for (int j = 14; j >= 0; --j) s[j] = add4(s[j], s[j + 1]);

    // ---- Pipelined main loop over 4 blocks of 16 ----
    #pragma unroll
    for (int blk = 0; blk < 4; ++blk) {
        const int tb = t0 + blk * 16;

        // Issue next block's loads before touching this block's data.
        float4 n[16];
        if (blk < 3) {
            #pragma unroll
            for (int k = 0; k < 16; ++k)
                n[k] = *(const float4*)(src + (size_t)(tb + 16 + k) * DD);
        }
        __builtin_amdgcn_sched_barrier(0);

        #pragma unroll
        for (int k = 0; k < 16; ++k) f[k] = exp4n(f[k]);

        float4 p = make_float4(0.f, 0.f, 0.f, 0.f);
        #pragma unroll
        for (int k = 0; k < 16; ++k) {
            p = add4(p, f[k]);
            const float4 w = (k < 15) ? add4(s[k + 1], p) : p;
            __builtin_nontemporal_store(
                mlog4(w), (vfloat4*)(dst + (size_t)(tb + k) * DD));
        }

        // Suffix of this block -> prev suffix for next block.
        s[15] = f[15];
        #pragma unroll
        for (int j = 14; j >= 0; --j) s[j] = add4(f[j], s[j + 1]);

        if (blk < 3) {
            #pragma unroll
            for (int k = 0; k < 16; ++k) f[k] = n[k];   // SSA, free
        }
    }
}

extern "C" void kernel_launch(void* const* d_in, const int* in_sizes, int n_in,
                              void* d_out, int out_size, void* d_ws, size_t ws_size,
                              hipStream_t stream)
{
    const float* lower = (const float*)d_in[0];
    const float* upper = (const float*)d_in[1];
    float* out = (float*)d_out;

    // waves = 8 seq-groups * 128 chunks = 1024 -> 256 blocks of 4 waves
    dim3 grid(256), block(256);
    hipLaunchKernelGGL(always_minish_v7, grid, block, 0, stream,
                       lower, upper, out);
}